// Round 1
// baseline (202.090 us; speedup 1.0000x reference)
//
#include <hip/hip_runtime.h>

#define NB   16
#define NC   3
#define NH   512
#define NW   512
#define OUTH 506
#define OUTW 506
#define TX   32
#define TY   32
#define PW   38          // patch width/height = TX+6
#define PST  40          // padded LDS stride

// -------- kernel 0: init workspace (runs every call; harness doesn't re-poison)
__global__ void ssim_init_ws(unsigned int* mn, unsigned int* mx, float* sum) {
    int i = threadIdx.x;
    if (i < NB) { mn[i] = 0x7f7fffffu; mx[i] = 0u; sum[i] = 0.0f; }
}

// -------- kernel 1: per-image min/max of pred (values >= 0 -> uint-bit order == float order)
__global__ __launch_bounds__(256) void ssim_minmax(const float* __restrict__ pred,
                                                   unsigned int* __restrict__ mn,
                                                   unsigned int* __restrict__ mx) {
    int b = blockIdx.y;
    const float4* p4 = (const float4*)(pred + (size_t)b * (NC * NH * NW));
    const int n4 = (NC * NH * NW) / 4;
    float lmin = 3.4e38f, lmax = -3.4e38f;
    for (int i = blockIdx.x * blockDim.x + threadIdx.x; i < n4; i += gridDim.x * blockDim.x) {
        float4 v = p4[i];
        lmin = fminf(lmin, fminf(fminf(v.x, v.y), fminf(v.z, v.w)));
        lmax = fmaxf(lmax, fmaxf(fmaxf(v.x, v.y), fmaxf(v.z, v.w)));
    }
    #pragma unroll
    for (int off = 32; off; off >>= 1) {
        lmin = fminf(lmin, __shfl_down(lmin, off, 64));
        lmax = fmaxf(lmax, __shfl_down(lmax, off, 64));
    }
    __shared__ float smin[4], smax[4];
    int wid = threadIdx.x >> 6, lane = threadIdx.x & 63;
    if (lane == 0) { smin[wid] = lmin; smax[wid] = lmax; }
    __syncthreads();
    if (threadIdx.x == 0) {
        float m = fminf(fminf(smin[0], smin[1]), fminf(smin[2], smin[3]));
        float M = fmaxf(fmaxf(smax[0], smax[1]), fmaxf(smax[2], smax[3]));
        atomicMin(&mn[b], __float_as_uint(m));
        atomicMax(&mx[b], __float_as_uint(M));
    }
}

// -------- kernel 2: tiled separable 7x7 SSIM, partial-sum per block -> atomicAdd per image
__global__ __launch_bounds__(256) void ssim_main(const float* __restrict__ t,
                                                 const float* __restrict__ p,
                                                 const unsigned int* __restrict__ mn,
                                                 const unsigned int* __restrict__ mx,
                                                 float* __restrict__ sum) {
    __shared__ float pt[PW * PST];
    __shared__ float pp[PW * PST];
    __shared__ float cs[5][TY * PST];
    __shared__ float part[4];

    const int b = blockIdx.z, ch = blockIdx.y;
    const int tx = blockIdx.x & 15, ty = blockIdx.x >> 4;
    const int row0 = ty * TY, col0 = tx * TX;
    const size_t base = ((size_t)(b * NC + ch)) * NH * NW;

    // stage 38x38 patch of t and p (clamped to image bounds; out-of-range outputs are guarded later)
    for (int e = threadIdx.x; e < PW * PW; e += 256) {
        int r = e / PW, c = e - r * PW;
        int gr = min(row0 + r, NH - 1);
        int gc = min(col0 + c, NW - 1);
        size_t idx = base + (size_t)gr * NW + gc;
        pt[r * PST + c] = t[idx];
        pp[r * PST + c] = p[idx];
    }
    __syncthreads();

    // vertical 7-sums of the five quantities
    for (int e = threadIdx.x; e < TY * PW; e += 256) {
        int i = e / PW, j = e - i * PW;
        float st = 0.f, sp = 0.f, stt = 0.f, spp = 0.f, stp = 0.f;
        #pragma unroll
        for (int k = 0; k < 7; ++k) {
            float a = pt[(i + k) * PST + j];
            float q = pp[(i + k) * PST + j];
            st += a; sp += q; stt += a * a; spp += q * q; stp += a * q;
        }
        int o = i * PST + j;
        cs[0][o] = st; cs[1][o] = sp; cs[2][o] = stt; cs[3][o] = spp; cs[4][o] = stp;
    }
    __syncthreads();

    const float dr = __uint_as_float(mx[b]) - __uint_as_float(mn[b]);
    const float c1 = (0.01f * dr) * (0.01f * dr);
    const float c2 = (0.03f * dr) * (0.03f * dr);
    const float inv_np = 1.0f / 49.0f;
    const float cov = 49.0f / 48.0f;

    float acc = 0.0f;
    #pragma unroll
    for (int k = 0; k < 4; ++k) {
        int o = threadIdx.x + k * 256;
        int i = o >> 5, j = o & 31;
        int gr = row0 + i, gc = col0 + j;
        if (gr < OUTH && gc < OUTW) {
            float st = 0.f, sp = 0.f, stt = 0.f, spp = 0.f, stp = 0.f;
            #pragma unroll
            for (int x = 0; x < 7; ++x) {
                int q = i * PST + j + x;
                st += cs[0][q]; sp += cs[1][q]; stt += cs[2][q]; spp += cs[3][q]; stp += cs[4][q];
            }
            float ux  = st  * inv_np, uy  = sp  * inv_np;
            float uxx = stt * inv_np, uyy = spp * inv_np, uxy = stp * inv_np;
            float vx  = cov * (uxx - ux * ux);
            float vy  = cov * (uyy - uy * uy);
            float vxy = cov * (uxy - ux * uy);
            float a1 = 2.0f * ux * uy + c1;
            float a2 = 2.0f * vxy + c2;
            float b1 = ux * ux + uy * uy + c1;
            float b2 = vx + vy + c2;
            acc += (a1 * a2) / (b1 * b2);
        }
    }

    #pragma unroll
    for (int off = 32; off; off >>= 1) acc += __shfl_down(acc, off, 64);
    int wid = threadIdx.x >> 6, lane = threadIdx.x & 63;
    if (lane == 0) part[wid] = acc;
    __syncthreads();
    if (threadIdx.x == 0)
        atomicAdd(&sum[b], part[0] + part[1] + part[2] + part[3]);
}

// -------- kernel 3: finalize mean
__global__ void ssim_finalize(const float* __restrict__ sum, float* __restrict__ out) {
    int i = threadIdx.x;
    if (i < NB) out[i] = sum[i] / (float)(NC * OUTH * OUTW);
}

extern "C" void kernel_launch(void* const* d_in, const int* in_sizes, int n_in,
                              void* d_out, int out_size, void* d_ws, size_t ws_size,
                              hipStream_t stream) {
    const float* t = (const float*)d_in[0];   // true
    const float* p = (const float*)d_in[1];   // pred
    float* out = (float*)d_out;

    unsigned int* mn  = (unsigned int*)d_ws;
    unsigned int* mx  = mn + NB;
    float*        sum = (float*)(mx + NB);

    ssim_init_ws<<<1, 64, 0, stream>>>(mn, mx, sum);
    ssim_minmax<<<dim3(64, NB), 256, 0, stream>>>(p, mn, mx);

    // 16x16 tiles of 32x32 outputs cover 506x506; grid = (tiles, C, B)
    ssim_main<<<dim3(256, NC, NB), 256, 0, stream>>>(t, p, mn, mx, sum);

    ssim_finalize<<<1, 64, 0, stream>>>(sum, out);
}

// Round 2
// 93.165 us; speedup vs baseline: 2.1692x; 2.1692x over previous
//
#include <hip/hip_runtime.h>

#define NB   16
#define NC   3
#define NH   512
#define NW   512
#define OUTH 506
#define OUTW 506
#define RPC  11          // output rows per chunk
#define NCHUNK 46        // 506 / 11
#define WPB  4           // waves per block (256 threads)

// -------- kernel 0: init workspace (runs every call; harness doesn't re-poison)
__global__ void ssim_init_ws(unsigned int* mn, unsigned int* mx, float* sum) {
    int i = threadIdx.x;
    if (i < NB) { mn[i] = 0x7f7fffffu; mx[i] = 0u; sum[i] = 0.0f; }
}

// -------- kernel 1: per-image min/max of pred (values >= 0 -> uint-bit order == float order)
__global__ __launch_bounds__(256) void ssim_minmax(const float* __restrict__ pred,
                                                   unsigned int* __restrict__ mn,
                                                   unsigned int* __restrict__ mx) {
    int b = blockIdx.y;
    const float4* p4 = (const float4*)(pred + (size_t)b * (NC * NH * NW));
    const int n4 = (NC * NH * NW) / 4;
    float lmin = 3.4e38f, lmax = -3.4e38f;
    for (int i = blockIdx.x * blockDim.x + threadIdx.x; i < n4; i += gridDim.x * blockDim.x) {
        float4 v = p4[i];
        lmin = fminf(lmin, fminf(fminf(v.x, v.y), fminf(v.z, v.w)));
        lmax = fmaxf(lmax, fmaxf(fmaxf(v.x, v.y), fmaxf(v.z, v.w)));
    }
    #pragma unroll
    for (int off = 32; off; off >>= 1) {
        lmin = fminf(lmin, __shfl_down(lmin, off, 64));
        lmax = fmaxf(lmax, __shfl_down(lmax, off, 64));
    }
    __shared__ float smin[4], smax[4];
    int wid = threadIdx.x >> 6, lane = threadIdx.x & 63;
    if (lane == 0) { smin[wid] = lmin; smax[wid] = lmax; }
    __syncthreads();
    if (threadIdx.x == 0) {
        float m = fminf(fminf(smin[0], smin[1]), fminf(smin[2], smin[3]));
        float M = fmaxf(fmaxf(smax[0], smax[1]), fmaxf(smax[2], smax[3]));
        atomicMin(&mn[b], __float_as_uint(m));
        atomicMax(&mx[b], __float_as_uint(M));
    }
}

// -------- kernel 2: register-resident separable sliding-window SSIM (no LDS)
// Each wave: one (image, channel, 11-row chunk), full 512-col width.
// Each lane: 8 output cols (c0..c0+7), tracks 14 cols of vertical running sums.
__global__ __launch_bounds__(256) void ssim_main(const float* __restrict__ tin,
                                                 const float* __restrict__ pin,
                                                 const unsigned int* __restrict__ mn,
                                                 const unsigned int* __restrict__ mx,
                                                 float* __restrict__ sum) {
    const int wid   = blockIdx.x * WPB + (threadIdx.x >> 6);
    const int lane  = threadIdx.x & 63;
    const int imgch = wid / NCHUNK;
    const int chunk = wid - imgch * NCHUNK;
    const int b     = imgch / NC;
    const int r0    = chunk * RPC;
    const int c0    = lane * 8;

    const float* tb = tin + (size_t)imgch * (NH * NW);
    const float* pb = pin + (size_t)imgch * (NH * NW);

    const float dr = __uint_as_float(mx[b]) - __uint_as_float(mn[b]);
    const float c1 = (0.01f * dr) * (0.01f * dr);
    const float c2 = (0.03f * dr) * (0.03f * dr);
    const float inv_np = 1.0f / 49.0f;
    const float cov = 49.0f / 48.0f;

    // vertical running sums for 14 tracked columns (c0 .. c0+13)
    float s_t[14], s_p[14], s_tt[14], s_pp[14], s_tp[14];
    #pragma unroll
    for (int i = 0; i < 14; ++i) {
        s_t[i] = 0.f; s_p[i] = 0.f; s_tt[i] = 0.f; s_pp[i] = 0.f; s_tp[i] = 0.f;
    }

    // column bases for the four float4 loads; clamp keeps lane 63 in-bounds
    // (its clamped duplicates feed only tracked cols >= 512, never a valid window)
    const int cb0 = c0;
    const int cb1 = c0 + 4;                  // max 508 = NW-4, in bounds
    const int cb2 = min(c0 + 8,  NW - 4);
    const int cb3 = min(c0 + 12, NW - 4);

    float acc = 0.f;

    for (int k = 0; k < RPC + 6; ++k) {
        const int rin = r0 + k;              // max 495+16 = 511, in bounds
        const float* trow = tb + rin * NW;
        const float* prow = pb + rin * NW;

        float te[16], pe[16];
        *(float4*)&te[0]  = *(const float4*)(trow + cb0);
        *(float4*)&te[4]  = *(const float4*)(trow + cb1);
        *(float4*)&te[8]  = *(const float4*)(trow + cb2);
        *(float4*)&te[12] = *(const float4*)(trow + cb3);
        *(float4*)&pe[0]  = *(const float4*)(prow + cb0);
        *(float4*)&pe[4]  = *(const float4*)(prow + cb1);
        *(float4*)&pe[8]  = *(const float4*)(prow + cb2);
        *(float4*)&pe[12] = *(const float4*)(prow + cb3);

        if (k >= 7) {                        // leaving row, re-load (L1/L2 hit)
            const float* tlr = tb + (rin - 7) * NW;
            const float* plr = pb + (rin - 7) * NW;
            float tl[16], pl[16];
            *(float4*)&tl[0]  = *(const float4*)(tlr + cb0);
            *(float4*)&tl[4]  = *(const float4*)(tlr + cb1);
            *(float4*)&tl[8]  = *(const float4*)(tlr + cb2);
            *(float4*)&tl[12] = *(const float4*)(tlr + cb3);
            *(float4*)&pl[0]  = *(const float4*)(plr + cb0);
            *(float4*)&pl[4]  = *(const float4*)(plr + cb1);
            *(float4*)&pl[8]  = *(const float4*)(plr + cb2);
            *(float4*)&pl[12] = *(const float4*)(plr + cb3);
            #pragma unroll
            for (int i = 0; i < 14; ++i) {
                float tv = tl[i], pv = pl[i];
                s_t[i]  -= tv;
                s_p[i]  -= pv;
                s_tt[i] = fmaf(-tv, tv, s_tt[i]);
                s_pp[i] = fmaf(-pv, pv, s_pp[i]);
                s_tp[i] = fmaf(-tv, pv, s_tp[i]);
            }
        }

        #pragma unroll
        for (int i = 0; i < 14; ++i) {
            float tv = te[i], pv = pe[i];
            s_t[i]  += tv;
            s_p[i]  += pv;
            s_tt[i] = fmaf(tv, tv, s_tt[i]);
            s_pp[i] = fmaf(pv, pv, s_pp[i]);
            s_tp[i] = fmaf(tv, pv, s_tp[i]);
        }

        if (k >= 6) {                        // emit output row r0 + k - 6
            float h_t  = s_t[0]+s_t[1]+s_t[2]+s_t[3]+s_t[4]+s_t[5]+s_t[6];
            float h_p  = s_p[0]+s_p[1]+s_p[2]+s_p[3]+s_p[4]+s_p[5]+s_p[6];
            float h_tt = s_tt[0]+s_tt[1]+s_tt[2]+s_tt[3]+s_tt[4]+s_tt[5]+s_tt[6];
            float h_pp = s_pp[0]+s_pp[1]+s_pp[2]+s_pp[3]+s_pp[4]+s_pp[5]+s_pp[6];
            float h_tp = s_tp[0]+s_tp[1]+s_tp[2]+s_tp[3]+s_tp[4]+s_tp[5]+s_tp[6];
            #pragma unroll
            for (int c = 0; c < 8; ++c) {
                if (c > 0) {
                    h_t  += s_t[c+6]  - s_t[c-1];
                    h_p  += s_p[c+6]  - s_p[c-1];
                    h_tt += s_tt[c+6] - s_tt[c-1];
                    h_pp += s_pp[c+6] - s_pp[c-1];
                    h_tp += s_tp[c+6] - s_tp[c-1];
                }
                if (c0 + c < OUTW) {
                    float ux  = h_t  * inv_np, uy  = h_p  * inv_np;
                    float uxx = h_tt * inv_np, uyy = h_pp * inv_np, uxy = h_tp * inv_np;
                    float vx  = cov * (uxx - ux * ux);
                    float vy  = cov * (uyy - uy * uy);
                    float vxy = cov * (uxy - ux * uy);
                    float a1 = 2.0f * ux * uy + c1;
                    float a2 = 2.0f * vxy + c2;
                    float b1 = ux * ux + uy * uy + c1;
                    float b2 = vx + vy + c2;
                    acc += (a1 * a2) / (b1 * b2);
                }
            }
        }
    }

    #pragma unroll
    for (int off = 32; off; off >>= 1) acc += __shfl_down(acc, off, 64);
    if (lane == 0) atomicAdd(&sum[b], acc);
}

// -------- kernel 3: finalize mean
__global__ void ssim_finalize(const float* __restrict__ sum, float* __restrict__ out) {
    int i = threadIdx.x;
    if (i < NB) out[i] = sum[i] / (float)(NC * OUTH * OUTW);
}

extern "C" void kernel_launch(void* const* d_in, const int* in_sizes, int n_in,
                              void* d_out, int out_size, void* d_ws, size_t ws_size,
                              hipStream_t stream) {
    const float* t = (const float*)d_in[0];   // true
    const float* p = (const float*)d_in[1];   // pred
    float* out = (float*)d_out;

    unsigned int* mn  = (unsigned int*)d_ws;
    unsigned int* mx  = mn + NB;
    float*        sum = (float*)(mx + NB);

    ssim_init_ws<<<1, 64, 0, stream>>>(mn, mx, sum);
    ssim_minmax<<<dim3(64, NB), 256, 0, stream>>>(p, mn, mx);

    // 2208 wave-tasks (16 img x 3 ch x 46 row-chunks), 4 waves per block
    ssim_main<<<dim3((NB * NC * NCHUNK) / WPB), 256, 0, stream>>>(t, p, mn, mx, sum);

    ssim_finalize<<<1, 64, 0, stream>>>(sum, out);
}